// Round 7
// baseline (275.919 us; speedup 1.0000x reference)
//
#include <hip/hip_runtime.h>
#include <hip/hip_bf16.h>

typedef __bf16 bf16x8 __attribute__((ext_vector_type(8)));
typedef float f32x4 __attribute__((ext_vector_type(4)));
typedef unsigned short u16;
typedef unsigned int u32;

#define DEVI __device__ __forceinline__
#define EXP2(x) __builtin_amdgcn_exp2f(x)
#define MFMA16(a, b, c) __builtin_amdgcn_mfma_f32_16x16x32_bf16(a, b, c, 0, 0, 0)

DEVI u16 f2bf(float f) {
  union { float f; u32 u; } v; v.f = f;
  u32 r = v.u + 0x7FFFu + ((v.u >> 16) & 1u);
  return (u16)(r >> 16);
}
DEVI u16 f2bf_t(float f) {  // truncating (P in [0,1]: err <= 2^-8 * P)
  union { float f; u32 u; } v; v.f = f;
  return (u16)(v.u >> 16);
}
DEVI float bf2f(u32 u) {
  union { u32 u; float f; } v; v.u = u << 16;
  return v.f;
}
DEVI bf16x8 ldg8(const u16* p) {
  union { int4 i; bf16x8 b; } u;
  u.i = *(const int4*)p;
  return u.b;
}
DEVI void gld16(const u16* g, u16* l) {
  __builtin_amdgcn_global_load_lds((const __attribute__((address_space(1))) u32*)g,
                                   (__attribute__((address_space(3))) u32*)l, 16, 0, 0);
}

constexpr float QSCALE = 0.125f * 1.44269504089f;  // 1/sqrt(dk) * log2(e)

// ---------------- f32 -> bf16 conversions (merged launches) ----------------
__global__ __launch_bounds__(256) void cvt_x2(const float* __restrict__ a,
                                              const float* __restrict__ bsrc,
                                              u16* __restrict__ oa, u16* __restrict__ ob) {
  const float* s = blockIdx.y ? bsrc : a;
  u16* d = blockIdx.y ? ob : oa;
  int i = (blockIdx.x * 256 + threadIdx.x) * 4;
  float4 f = *(const float4*)(s + i);
  ushort4 o;
  o.x = f2bf(f.x); o.y = f2bf(f.y); o.z = f2bf(f.z); o.w = f2bf(f.w);
  *(ushort4*)(d + i) = o;
}

__global__ __launch_bounds__(256) void cvt_w4(const float* __restrict__ w0, const float* __restrict__ w1,
                                              const float* __restrict__ w2, const float* __restrict__ w3,
                                              u16* __restrict__ o0, u16* __restrict__ o1,
                                              u16* __restrict__ o2, u16* __restrict__ o3) {
  int y = blockIdx.y;
  const float* s = (y == 0) ? w0 : (y == 1) ? w1 : (y == 2) ? w2 : w3;
  u16* d = (y == 0) ? o0 : (y == 1) ? o1 : (y == 2) ? o2 : o3;
  int i = (blockIdx.x * 256 + threadIdx.x) * 4;
  float4 f = *(const float4*)(s + i);
  ushort4 o;
  o.x = f2bf(f.x); o.y = f2bf(f.y); o.z = f2bf(f.z); o.w = f2bf(f.w);
  *(ushort4*)(d + i) = o;
}

// ------- fused QKV projection: C[i][j] = sum_k A[i][k]*W[j][k] + bias[j] ----
__global__ __launch_bounds__(256) void gemm_qkv(const u16* __restrict__ XQ,
                                                const u16* __restrict__ XKV,
                                                const u16* __restrict__ WQ,
                                                const u16* __restrict__ WK,
                                                const u16* __restrict__ WV,
                                                const float* __restrict__ bqp,
                                                const float* __restrict__ bkp,
                                                const float* __restrict__ bvp,
                                                u16* __restrict__ Qo,
                                                u16* __restrict__ Ko,
                                                u16* __restrict__ Vo) {
  constexpr int K = 1024, N = 1024;
  const int z = blockIdx.z;
  const u16* A = (z == 0) ? XQ : XKV;
  const u16* W = (z == 0) ? WQ : (z == 1) ? WK : WV;
  const float* bias = (z == 0) ? bqp : (z == 1) ? bkp : bvp;
  u16* C = (z == 0) ? Qo : (z == 1) ? Ko : Vo;
  const float scale = (z == 0) ? QSCALE : 1.0f;

  __shared__ u16 sA[128 * 32], sB[128 * 32];
  const int t = threadIdx.x, w = t >> 6, l = t & 63;
  const int wm = w >> 1, wn = w & 1;
  const int lr = l & 15, lk = (l >> 4) * 8, lg = (l >> 4) * 4;
  const int rowA0 = blockIdx.y * 128, colB0 = blockIdx.x * 128;
  const int srow = l >> 2, scol = (l & 3) * 8;
  const u16* gA0 = A + (size_t)(rowA0 + w * 32 + srow) * K + scol;
  const u16* gA1 = gA0 + (size_t)16 * K;
  const u16* gB0 = W + (size_t)(colB0 + w * 32 + srow) * K + scol;
  const u16* gB1 = gB0 + (size_t)16 * K;
  u16* lA0 = sA + w * 1024;
  u16* lA1 = sA + w * 1024 + 512;
  u16* lB0 = sB + w * 1024;
  u16* lB1 = sB + w * 1024 + 512;
  f32x4 acc[4][4] = {};
  for (int k0 = 0; k0 < K; k0 += 32) {
    __syncthreads();
    gld16(gA0 + k0, lA0);
    gld16(gA1 + k0, lA1);
    gld16(gB0 + k0, lB0);
    gld16(gB1 + k0, lB1);
    __syncthreads();
    bf16x8 af[4], bfr[4];
#pragma unroll
    for (int m = 0; m < 4; ++m)
      af[m] = *(const bf16x8*)(sA + (wm * 64 + m * 16 + lr) * 32 + lk);
#pragma unroll
    for (int n = 0; n < 4; ++n)
      bfr[n] = *(const bf16x8*)(sB + (wn * 64 + n * 16 + lr) * 32 + lk);
#pragma unroll
    for (int m = 0; m < 4; ++m)
#pragma unroll
      for (int n = 0; n < 4; ++n)
        acc[m][n] = MFMA16(af[m], bfr[n], acc[m][n]);
  }
#pragma unroll
  for (int m = 0; m < 4; ++m) {
    int row = rowA0 + wm * 64 + m * 16 + lg;
#pragma unroll
    for (int n = 0; n < 4; ++n) {
      int col = colB0 + wn * 64 + n * 16 + lr;
      float bs = bias[col];
#pragma unroll
      for (int r = 0; r < 4; ++r)
        C[(size_t)(row + r) * N + col] = f2bf((acc[m][n][r] + bs) * scale);
    }
  }
}

// ---------------- O projection: f32 out. BM=64, BN=128, BK=32, 512 blocks ---
__global__ __launch_bounds__(256) void gemm_o(const u16* __restrict__ A,
                                              const u16* __restrict__ W,
                                              const float* __restrict__ bias,
                                              float* __restrict__ Cv) {
  constexpr int K = 1024, N = 1024;
  __shared__ u16 sA[64 * 32], sB[128 * 32];
  const int t = threadIdx.x, w = t >> 6, l = t & 63;
  const int wm = w >> 1, wn = w & 1;
  const int lr = l & 15, lk = (l >> 4) * 8, lg = (l >> 4) * 4;
  const int rowA0 = blockIdx.y * 64, colB0 = blockIdx.x * 128;
  const int srow = l >> 2, scol = (l & 3) * 8;
  const u16* gA  = A + (size_t)(rowA0 + w * 16 + srow) * K + scol;
  const u16* gB0 = W + (size_t)(colB0 + w * 32 + srow) * K + scol;
  const u16* gB1 = gB0 + (size_t)16 * K;
  u16* lA  = sA + w * 512;
  u16* lB0 = sB + w * 1024;
  u16* lB1 = sB + w * 1024 + 512;
  f32x4 acc[2][4] = {};
  for (int k0 = 0; k0 < K; k0 += 32) {
    __syncthreads();
    gld16(gA + k0, lA);
    gld16(gB0 + k0, lB0);
    gld16(gB1 + k0, lB1);
    __syncthreads();
    bf16x8 af[2], bfr[4];
#pragma unroll
    for (int m = 0; m < 2; ++m)
      af[m] = *(const bf16x8*)(sA + (wm * 32 + m * 16 + lr) * 32 + lk);
#pragma unroll
    for (int n = 0; n < 4; ++n)
      bfr[n] = *(const bf16x8*)(sB + (wn * 64 + n * 16 + lr) * 32 + lk);
#pragma unroll
    for (int m = 0; m < 2; ++m)
#pragma unroll
      for (int n = 0; n < 4; ++n)
        acc[m][n] = MFMA16(af[m], bfr[n], acc[m][n]);
  }
#pragma unroll
  for (int m = 0; m < 2; ++m) {
    int row = rowA0 + wm * 32 + m * 16 + lg;
#pragma unroll
    for (int n = 0; n < 4; ++n) {
      int col = colB0 + wn * 64 + n * 16 + lr;
      float bs = bias[col];
#pragma unroll
      for (int r = 0; r < 4; ++r)
        Cv[(size_t)(row + r) * N + col] = acc[m][n][r] + bs;
    }
  }
}

// ---------------- fused causal attention, writes attn (f32) + O (bf16) ------
// grid: (qtile=32 reversed, h=16, b=2) = 1024 blocks -> 4 blocks/CU.
// Pass 1: NO LDS, NO barriers — K fragments ldg8'd straight from L2 with a
// register double-buffer (K panel is 256 KB/head: L2-resident). Waves run
// fully independent. Pass 2 keeps LDS staging (sVt needs cross-wave share).
__global__ __launch_bounds__(256) void attn_fused(const u16* __restrict__ Qb,
                                                  const u16* __restrict__ Kb,
                                                  const u16* __restrict__ Vb,
                                                  float* __restrict__ attn,
                                                  u16* __restrict__ Ob) {
  constexpr int Tn = 2048, Dn = 1024, LDK = 72;
  const int qt = 31 - blockIdx.x, h = blockIdx.y, b = blockIdx.z;
  const int t = threadIdx.x, w = t >> 6, l = t & 63;
  const int lr = l & 15, lk = (l >> 4) * 8, lg = (l >> 4) * 4;
  __shared__ u16 sK[64 * LDK];
  __shared__ u16 sVt[64 * LDK];   // [dk][key]
  __shared__ u16 sP[64 * LDK];

  const u16* KgB = Kb + (size_t)b * Tn * Dn + h * 64;
  const u16* VgB = Vb + (size_t)b * Tn * Dn + h * 64;
  const u16* KgL = KgB + (size_t)lr * Dn + lk;  // per-lane K fragment base
  const int skey = t >> 3, skc = (t & 7) * 8;

  // Q fragments for this wave's 16 rows
  bf16x8 qf[2];
  {
    int row = b * Tn + qt * 64 + w * 16 + lr;
#pragma unroll
    for (int ks = 0; ks < 2; ++ks)
      qf[ks] = ldg8(Qb + (size_t)row * Dn + h * 64 + ks * 32 + lk);
  }

  const int nkt = qt + 1;
  const int qg = qt * 64 + w * 16 + lg;
  float psum[4] = {};

#define LOADK(K0, K1, kb_) { \
    const u16* _p = KgL + (size_t)(kb_)*Dn; \
    K0[0] = ldg8(_p); K1[0] = ldg8(_p + 32); _p += (size_t)16 * Dn; \
    K0[1] = ldg8(_p); K1[1] = ldg8(_p + 32); _p += (size_t)16 * Dn; \
    K0[2] = ldg8(_p); K1[2] = ldg8(_p + 32); _p += (size_t)16 * Dn; \
    K0[3] = ldg8(_p); K1[3] = ldg8(_p + 32); }

#define QKSUM(K0, K1, kt_) { \
    f32x4 s0 = {}, s1 = {}, s2 = {}, s3 = {}; \
    s0 = MFMA16(qf[0], K0[0], s0); s0 = MFMA16(qf[1], K1[0], s0); \
    s1 = MFMA16(qf[0], K0[1], s1); s1 = MFMA16(qf[1], K1[1], s1); \
    s2 = MFMA16(qf[0], K0[2], s2); s2 = MFMA16(qf[1], K1[2], s2); \
    s3 = MFMA16(qf[0], K0[3], s3); s3 = MFMA16(qf[1], K1[3], s3); \
    if ((kt_) < qt) { \
      _Pragma("unroll") for (int r = 0; r < 4; ++r) \
        psum[r] += EXP2(s0[r]) + EXP2(s1[r]) + EXP2(s2[r]) + EXP2(s3[r]); \
    } else { \
      const int _kb = (kt_)*64; \
      _Pragma("unroll") for (int r = 0; r < 4; ++r) { \
        float e0 = EXP2(s0[r]), e1 = EXP2(s1[r]), e2 = EXP2(s2[r]), e3 = EXP2(s3[r]); \
        psum[r] += ((_kb +  0 + lr <= qg + r) ? e0 : 0.f) + ((_kb + 16 + lr <= qg + r) ? e1 : 0.f) \
                 + ((_kb + 32 + lr <= qg + r) ? e2 : 0.f) + ((_kb + 48 + lr <= qg + r) ? e3 : 0.f); \
      } \
    } }

  // ---- pass 1: barrier-free, reg-double-buffered K direct from L2 ----
  {
    bf16x8 kA0[4], kA1[4], kB0[4], kB1[4];
    LOADK(kA0, kA1, 0);
    for (int kt = 0; kt < nkt; kt += 2) {
      if (kt + 1 < nkt) LOADK(kB0, kB1, (kt + 1) * 64);
      QKSUM(kA0, kA1, kt);
      if (kt + 1 < nkt) {
        if (kt + 2 < nkt) LOADK(kA0, kA1, (kt + 2) * 64);
        QKSUM(kB0, kB1, kt + 1);
      }
    }
  }

  // prologue loads for pass 2 tile 0 (land during the reduce below)
  int4 kr0, kr1, vr0, vr1;
  kr0 = *(const int4*)(KgB + (size_t)skey * Dn + skc);
  kr1 = *(const int4*)(KgB + (size_t)(32 + skey) * Dn + skc);
  vr0 = *(const int4*)(VgB + (size_t)l * Dn + w * 8);
  vr1 = *(const int4*)(VgB + (size_t)l * Dn + (4 + w) * 8);

  float inv[4];
#pragma unroll
  for (int r = 0; r < 4; ++r) {
    float v = psum[r];
#pragma unroll
    for (int d = 1; d < 16; d <<= 1) v += __shfl_xor(v, d);
    inv[r] = __builtin_amdgcn_rcpf(v);
  }

  float* attnBH = attn + (size_t)(b * 16 + h) * Tn * Tn;
  f32x4 accO[4] = {};

  // ---- pass 2: recompute S, normalized P -> sP(bf16), PV, nt stores -------
  for (int kt = 0; kt < nkt; ++kt) {
    __syncthreads();  // prev tile's QK/PV done reading sK/sVt
    *(int4*)(sK + skey * LDK + skc) = kr0;
    *(int4*)(sK + (32 + skey) * LDK + skc) = kr1;
    {
      const u16* pv0 = (const u16*)&vr0;
      const u16* pv1 = (const u16*)&vr1;
#pragma unroll
      for (int j = 0; j < 8; ++j) {
        sVt[(w * 8 + j) * LDK + l] = pv0[j];
        sVt[((4 + w) * 8 + j) * LDK + l] = pv1[j];
      }
    }
    if (kt + 1 < nkt) {
      const u16* pk = KgB + (size_t)((kt + 1) * 64) * Dn;
      const u16* pv = VgB + (size_t)((kt + 1) * 64) * Dn;
      kr0 = *(const int4*)(pk + (size_t)skey * Dn + skc);
      kr1 = *(const int4*)(pk + (size_t)(32 + skey) * Dn + skc);
      vr0 = *(const int4*)(pv + (size_t)l * Dn + w * 8);
      vr1 = *(const int4*)(pv + (size_t)l * Dn + (4 + w) * 8);
    }
    __syncthreads();  // sK/sVt ready
    const int kb = kt * 64;
    f32x4 s[4] = {};
#pragma unroll
    for (int nf = 0; nf < 4; ++nf)
#pragma unroll
      for (int ks = 0; ks < 2; ++ks) {
        bf16x8 kf = *(const bf16x8*)(sK + (nf * 16 + lr) * LDK + ks * 32 + lk);
        s[nf] = MFMA16(qf[ks], kf, s[nf]);
      }
    const int prow = w * 16 + lg;
    if (kt < qt) {
#pragma unroll
      for (int r = 0; r < 4; ++r)
#pragma unroll
        for (int nf = 0; nf < 4; ++nf)
          sP[(prow + r) * LDK + nf * 16 + lr] = f2bf_t(EXP2(s[nf][r]) * inv[r]);
    } else {
#pragma unroll
      for (int r = 0; r < 4; ++r)
#pragma unroll
        for (int nf = 0; nf < 4; ++nf) {
          float p = (kb + nf * 16 + lr <= qg + r) ? EXP2(s[nf][r]) * inv[r] : 0.f;
          sP[(prow + r) * LDK + nf * 16 + lr] = f2bf_t(p);
        }
    }
    // no barrier: sP rows are per-wave; intra-wave lgkmcnt ordering suffices
#pragma unroll
    for (int ks = 0; ks < 2; ++ks) {
      bf16x8 ap, bv[4];
      ap = *(const bf16x8*)(sP + (w * 16 + lr) * LDK + ks * 32 + lk);
#pragma unroll
      for (int nf = 0; nf < 4; ++nf)
        bv[nf] = *(const bf16x8*)(sVt + (nf * 16 + lr) * LDK + ks * 32 + lk);
#pragma unroll
      for (int nf = 0; nf < 4; ++nf)
        accO[nf] = MFMA16(ap, bv[nf], accO[nf]);
    }
    // per-wave coalesced non-temporal f32 attn stores of this wave's 16 rows
#pragma unroll
    for (int i = 0; i < 4; ++i) {
      int fidx = i * 64 + l;
      int row = w * 16 + (fidx >> 4), c4 = fidx & 15;
      uint2 pk = *(const uint2*)(sP + row * LDK + c4 * 4);
      f32x4 o;
      o[0] = bf2f(pk.x & 0xffffu);
      o[1] = bf2f(pk.x >> 16);
      o[2] = bf2f(pk.y & 0xffffu);
      o[3] = bf2f(pk.y >> 16);
      __builtin_nontemporal_store(o, (f32x4*)(attnBH + (size_t)(qt * 64 + row) * Tn + kb + c4 * 4));
    }
  }

  // zero-fill columns beyond causal extent of this q-tile (non-temporal)
  {
    const int zstart = nkt * 64;
    if (zstart < Tn) {
      f32x4 z4 = {0.f, 0.f, 0.f, 0.f};
      for (int rr = 0; rr < 64; ++rr) {
        float* rp = attnBH + (size_t)(qt * 64 + rr) * Tn;
        for (int cc = zstart + 4 * t; cc < Tn; cc += 1024)
          __builtin_nontemporal_store(z4, (f32x4*)(rp + cc));
      }
    }
  }

  // O (bf16) into [B*T][D] at this head's column block
  {
    int row = b * Tn + qt * 64 + w * 16 + lg;
#pragma unroll
    for (int nf = 0; nf < 4; ++nf) {
      int col = h * 64 + nf * 16 + lr;
#pragma unroll
      for (int r = 0; r < 4; ++r)
        Ob[(size_t)(row + r) * Dn + col] = f2bf(accO[nf][r]);
    }
  }
#undef LOADK
#undef QKSUM
}

extern "C" void kernel_launch(void* const* d_in, const int* in_sizes, int n_in,
                              void* d_out, int out_size, void* d_ws, size_t ws_size,
                              hipStream_t stream) {
  const float* xq  = (const float*)d_in[0];
  const float* xkv = (const float*)d_in[1];
  // d_in[2] = mask (causal, implicit)
  const float* Wq = (const float*)d_in[3];
  const float* bq = (const float*)d_in[4];
  const float* Wk = (const float*)d_in[5];
  const float* bk = (const float*)d_in[6];
  const float* Wv = (const float*)d_in[7];
  const float* bv = (const float*)d_in[8];
  const float* Wo = (const float*)d_in[9];
  const float* bo = (const float*)d_in[10];

  float* out  = (float*)d_out;                  // [4096][1024]
  float* attn = out + (size_t)4096 * 1024;      // [2][16][2048][2048]

  u16* XQ  = (u16*)d_ws;
  u16* XKV = XQ  + (size_t)4096 * 1024;
  u16* WQb = XKV + (size_t)4096 * 1024;
  u16* WKb = WQb + (size_t)1024 * 1024;
  u16* WVb = WKb + (size_t)1024 * 1024;
  u16* WOb = WVb + (size_t)1024 * 1024;
  u16* Qb  = WOb + (size_t)1024 * 1024;
  u16* Kb  = Qb  + (size_t)4096 * 1024;
  u16* Vb  = Kb  + (size_t)4096 * 1024;
  u16* Ob  = Vb  + (size_t)4096 * 1024;

  cvt_x2<<<dim3(4096, 2), 256, 0, stream>>>(xq, xkv, XQ, XKV);
  cvt_w4<<<dim3(1024, 4), 256, 0, stream>>>(Wq, Wk, Wv, Wo, WQb, WKb, WVb, WOb);

  gemm_qkv<<<dim3(8, 32, 3), 256, 0, stream>>>(XQ, XKV, WQb, WKb, WVb,
                                               bq, bk, bv, Qb, Kb, Vb);

  attn_fused<<<dim3(32, 16, 2), 256, 0, stream>>>(Qb, Kb, Vb, attn, Ob);

  gemm_o<<<dim3(8, 64), 256, 0, stream>>>(Ob, WOb, bo, out);
}

// Round 8
// 238.046 us; speedup vs baseline: 1.1591x; 1.1591x over previous
//
#include <hip/hip_runtime.h>
#include <hip/hip_bf16.h>

typedef __bf16 bf16x8 __attribute__((ext_vector_type(8)));
typedef float f32x4 __attribute__((ext_vector_type(4)));
typedef unsigned short u16;
typedef unsigned int u32;

#define DEVI __device__ __forceinline__
#define EXP2(x) __builtin_amdgcn_exp2f(x)
#define MFMA16(a, b, c) __builtin_amdgcn_mfma_f32_16x16x32_bf16(a, b, c, 0, 0, 0)

DEVI u16 f2bf(float f) {
  union { float f; u32 u; } v; v.f = f;
  u32 r = v.u + 0x7FFFu + ((v.u >> 16) & 1u);
  return (u16)(r >> 16);
}
DEVI u16 f2bf_t(float f) {  // truncating (P in [0,1]: err <= 2^-8 * P)
  union { float f; u32 u; } v; v.f = f;
  return (u16)(v.u >> 16);
}
DEVI float bf2f(u32 u) {
  union { u32 u; float f; } v; v.u = u << 16;
  return v.f;
}
DEVI bf16x8 ldg8(const u16* p) {
  union { int4 i; bf16x8 b; } u;
  u.i = *(const int4*)p;
  return u.b;
}
DEVI void gld16(const u16* g, u16* l) {
  __builtin_amdgcn_global_load_lds((const __attribute__((address_space(1))) u32*)g,
                                   (__attribute__((address_space(3))) u32*)l, 16, 0, 0);
}

constexpr float QSCALE = 0.125f * 1.44269504089f;  // 1/sqrt(dk) * log2(e)

// ---------------- f32 -> bf16 conversions (merged launches) ----------------
__global__ __launch_bounds__(256) void cvt_x2(const float* __restrict__ a,
                                              const float* __restrict__ bsrc,
                                              u16* __restrict__ oa, u16* __restrict__ ob) {
  const float* s = blockIdx.y ? bsrc : a;
  u16* d = blockIdx.y ? ob : oa;
  int i = (blockIdx.x * 256 + threadIdx.x) * 4;
  float4 f = *(const float4*)(s + i);
  ushort4 o;
  o.x = f2bf(f.x); o.y = f2bf(f.y); o.z = f2bf(f.z); o.w = f2bf(f.w);
  *(ushort4*)(d + i) = o;
}

__global__ __launch_bounds__(256) void cvt_w4(const float* __restrict__ w0, const float* __restrict__ w1,
                                              const float* __restrict__ w2, const float* __restrict__ w3,
                                              u16* __restrict__ o0, u16* __restrict__ o1,
                                              u16* __restrict__ o2, u16* __restrict__ o3) {
  int y = blockIdx.y;
  const float* s = (y == 0) ? w0 : (y == 1) ? w1 : (y == 2) ? w2 : w3;
  u16* d = (y == 0) ? o0 : (y == 1) ? o1 : (y == 2) ? o2 : o3;
  int i = (blockIdx.x * 256 + threadIdx.x) * 4;
  float4 f = *(const float4*)(s + i);
  ushort4 o;
  o.x = f2bf(f.x); o.y = f2bf(f.y); o.z = f2bf(f.z); o.w = f2bf(f.w);
  *(ushort4*)(d + i) = o;
}

// ------- fused QKV projection: C[i][j] = sum_k A[i][k]*W[j][k] + bias[j] ----
__global__ __launch_bounds__(256) void gemm_qkv(const u16* __restrict__ XQ,
                                                const u16* __restrict__ XKV,
                                                const u16* __restrict__ WQ,
                                                const u16* __restrict__ WK,
                                                const u16* __restrict__ WV,
                                                const float* __restrict__ bqp,
                                                const float* __restrict__ bkp,
                                                const float* __restrict__ bvp,
                                                u16* __restrict__ Qo,
                                                u16* __restrict__ Ko,
                                                u16* __restrict__ Vo) {
  constexpr int K = 1024, N = 1024;
  const int z = blockIdx.z;
  const u16* A = (z == 0) ? XQ : XKV;
  const u16* W = (z == 0) ? WQ : (z == 1) ? WK : WV;
  const float* bias = (z == 0) ? bqp : (z == 1) ? bkp : bvp;
  u16* C = (z == 0) ? Qo : (z == 1) ? Ko : Vo;
  const float scale = (z == 0) ? QSCALE : 1.0f;

  __shared__ u16 sA[128 * 32], sB[128 * 32];
  const int t = threadIdx.x, w = t >> 6, l = t & 63;
  const int wm = w >> 1, wn = w & 1;
  const int lr = l & 15, lk = (l >> 4) * 8, lg = (l >> 4) * 4;
  const int rowA0 = blockIdx.y * 128, colB0 = blockIdx.x * 128;
  const int srow = l >> 2, scol = (l & 3) * 8;
  const u16* gA0 = A + (size_t)(rowA0 + w * 32 + srow) * K + scol;
  const u16* gA1 = gA0 + (size_t)16 * K;
  const u16* gB0 = W + (size_t)(colB0 + w * 32 + srow) * K + scol;
  const u16* gB1 = gB0 + (size_t)16 * K;
  u16* lA0 = sA + w * 1024;
  u16* lA1 = sA + w * 1024 + 512;
  u16* lB0 = sB + w * 1024;
  u16* lB1 = sB + w * 1024 + 512;
  f32x4 acc[4][4] = {};
  for (int k0 = 0; k0 < K; k0 += 32) {
    __syncthreads();
    gld16(gA0 + k0, lA0);
    gld16(gA1 + k0, lA1);
    gld16(gB0 + k0, lB0);
    gld16(gB1 + k0, lB1);
    __syncthreads();
    bf16x8 af[4], bfr[4];
#pragma unroll
    for (int m = 0; m < 4; ++m)
      af[m] = *(const bf16x8*)(sA + (wm * 64 + m * 16 + lr) * 32 + lk);
#pragma unroll
    for (int n = 0; n < 4; ++n)
      bfr[n] = *(const bf16x8*)(sB + (wn * 64 + n * 16 + lr) * 32 + lk);
#pragma unroll
    for (int m = 0; m < 4; ++m)
#pragma unroll
      for (int n = 0; n < 4; ++n)
        acc[m][n] = MFMA16(af[m], bfr[n], acc[m][n]);
  }
#pragma unroll
  for (int m = 0; m < 4; ++m) {
    int row = rowA0 + wm * 64 + m * 16 + lg;
#pragma unroll
    for (int n = 0; n < 4; ++n) {
      int col = colB0 + wn * 64 + n * 16 + lr;
      float bs = bias[col];
#pragma unroll
      for (int r = 0; r < 4; ++r)
        C[(size_t)(row + r) * N + col] = f2bf((acc[m][n][r] + bs) * scale);
    }
  }
}

// ---------------- O projection: f32 out. BM=64, BN=128, BK=32, 512 blocks ---
__global__ __launch_bounds__(256) void gemm_o(const u16* __restrict__ A,
                                              const u16* __restrict__ W,
                                              const float* __restrict__ bias,
                                              float* __restrict__ Cv) {
  constexpr int K = 1024, N = 1024;
  __shared__ u16 sA[64 * 32], sB[128 * 32];
  const int t = threadIdx.x, w = t >> 6, l = t & 63;
  const int wm = w >> 1, wn = w & 1;
  const int lr = l & 15, lk = (l >> 4) * 8, lg = (l >> 4) * 4;
  const int rowA0 = blockIdx.y * 64, colB0 = blockIdx.x * 128;
  const int srow = l >> 2, scol = (l & 3) * 8;
  const u16* gA  = A + (size_t)(rowA0 + w * 16 + srow) * K + scol;
  const u16* gB0 = W + (size_t)(colB0 + w * 32 + srow) * K + scol;
  const u16* gB1 = gB0 + (size_t)16 * K;
  u16* lA  = sA + w * 512;
  u16* lB0 = sB + w * 1024;
  u16* lB1 = sB + w * 1024 + 512;
  f32x4 acc[2][4] = {};
  for (int k0 = 0; k0 < K; k0 += 32) {
    __syncthreads();
    gld16(gA + k0, lA);
    gld16(gB0 + k0, lB0);
    gld16(gB1 + k0, lB1);
    __syncthreads();
    bf16x8 af[2], bfr[4];
#pragma unroll
    for (int m = 0; m < 2; ++m)
      af[m] = *(const bf16x8*)(sA + (wm * 32 + m * 16 + lr) * 32 + lk);
#pragma unroll
    for (int n = 0; n < 4; ++n)
      bfr[n] = *(const bf16x8*)(sB + (wn * 64 + n * 16 + lr) * 32 + lk);
#pragma unroll
    for (int m = 0; m < 2; ++m)
#pragma unroll
      for (int n = 0; n < 4; ++n)
        acc[m][n] = MFMA16(af[m], bfr[n], acc[m][n]);
  }
#pragma unroll
  for (int m = 0; m < 2; ++m) {
    int row = rowA0 + wm * 32 + m * 16 + lg;
#pragma unroll
    for (int n = 0; n < 4; ++n) {
      int col = colB0 + wn * 64 + n * 16 + lr;
      float bs = bias[col];
#pragma unroll
      for (int r = 0; r < 4; ++r)
        Cv[(size_t)(row + r) * N + col] = acc[m][n][r] + bs;
    }
  }
}

// ---------------- fused causal attention, writes attn (f32) + O (bf16) ------
// grid: (qtile=32 reversed, h=16, b=2) = 1024 blocks -> 4 blocks/CU.
// R6 LDS-staged structure, but with raw-barrier discipline (T4): barriers
// never drain vmcnt, so prefetched K/V loads and nt attn stores stay in
// flight across tiles. lgkmcnt(0)-only before the "data ready" barrier.
__global__ __launch_bounds__(256) void attn_fused(const u16* __restrict__ Qb,
                                                  const u16* __restrict__ Kb,
                                                  const u16* __restrict__ Vb,
                                                  float* __restrict__ attn,
                                                  u16* __restrict__ Ob) {
  constexpr int Tn = 2048, Dn = 1024, LDK = 72;
  const int qt = 31 - blockIdx.x, h = blockIdx.y, b = blockIdx.z;
  const int t = threadIdx.x, w = t >> 6, l = t & 63;
  const int lr = l & 15, lk = (l >> 4) * 8, lg = (l >> 4) * 4;
  __shared__ u16 sK[64 * LDK];
  __shared__ u16 sVt[64 * LDK];   // [dk][key]
  __shared__ u16 sP[64 * LDK];

  const u16* KgB = Kb + (size_t)b * Tn * Dn + h * 64;
  const u16* VgB = Vb + (size_t)b * Tn * Dn + h * 64;
  const int skey = t >> 3, skc = (t & 7) * 8;  // K staging coords (2 halves)

  // Q fragments for this wave's 16 rows
  bf16x8 qf[2];
  {
    int row = b * Tn + qt * 64 + w * 16 + lr;
#pragma unroll
    for (int ks = 0; ks < 2; ++ks)
      qf[ks] = ldg8(Qb + (size_t)row * Dn + h * 64 + ks * 32 + lk);
  }

  const int nkt = qt + 1;
  const int qg = qt * 64 + w * 16 + lg;
  float psum[4] = {};
  int4 kr0, kr1, vr0, vr1;

  // ---- pass 1: per-row sum of exp2(s); no vmcnt drain at barriers ----
  kr0 = *(const int4*)(KgB + (size_t)skey * Dn + skc);
  kr1 = *(const int4*)(KgB + (size_t)(32 + skey) * Dn + skc);
  for (int kt = 0; kt < nkt; ++kt) {
    __builtin_amdgcn_s_barrier();        // A: all waves consumed sK of kt-1
    __builtin_amdgcn_sched_barrier(0);
    *(int4*)(sK + skey * LDK + skc) = kr0;
    *(int4*)(sK + (32 + skey) * LDK + skc) = kr1;
    if (kt + 1 < nkt) {
      const u16* p = KgB + (size_t)((kt + 1) * 64) * Dn;
      kr0 = *(const int4*)(p + (size_t)skey * Dn + skc);
      kr1 = *(const int4*)(p + (size_t)(32 + skey) * Dn + skc);
    }
    asm volatile("s_waitcnt lgkmcnt(0)" ::: "memory");
    __builtin_amdgcn_s_barrier();        // B: sK visible to all waves
    __builtin_amdgcn_sched_barrier(0);
    const int kb = kt * 64;
    f32x4 s[4] = {};
#pragma unroll
    for (int nf = 0; nf < 4; ++nf)
#pragma unroll
      for (int ks = 0; ks < 2; ++ks) {
        bf16x8 kf = *(const bf16x8*)(sK + (nf * 16 + lr) * LDK + ks * 32 + lk);
        s[nf] = MFMA16(qf[ks], kf, s[nf]);
      }
    if (kt < qt) {  // fully-valid tile
#pragma unroll
      for (int r = 0; r < 4; ++r)
        psum[r] += EXP2(s[0][r]) + EXP2(s[1][r]) + EXP2(s[2][r]) + EXP2(s[3][r]);
    } else {
#pragma unroll
      for (int r = 0; r < 4; ++r)
#pragma unroll
        for (int nf = 0; nf < 4; ++nf) {
          float e = EXP2(s[nf][r]);
          psum[r] += (kb + nf * 16 + lr <= qg + r) ? e : 0.f;
        }
    }
  }

  // prologue loads for pass 2 tile 0 (land during the reduce below)
  kr0 = *(const int4*)(KgB + (size_t)skey * Dn + skc);
  kr1 = *(const int4*)(KgB + (size_t)(32 + skey) * Dn + skc);
  vr0 = *(const int4*)(VgB + (size_t)l * Dn + w * 8);
  vr1 = *(const int4*)(VgB + (size_t)l * Dn + (4 + w) * 8);

  float inv[4];
#pragma unroll
  for (int r = 0; r < 4; ++r) {
    float v = psum[r];
#pragma unroll
    for (int d = 1; d < 16; d <<= 1) v += __shfl_xor(v, d);
    inv[r] = __builtin_amdgcn_rcpf(v);
  }

  float* attnBH = attn + (size_t)(b * 16 + h) * Tn * Tn;
  f32x4 accO[4] = {};

  // ---- pass 2: recompute S, normalized P -> sP(bf16), PV, nt stores -------
  for (int kt = 0; kt < nkt; ++kt) {
    __builtin_amdgcn_s_barrier();        // A: all waves consumed sK/sVt of kt-1
    __builtin_amdgcn_sched_barrier(0);
    *(int4*)(sK + skey * LDK + skc) = kr0;
    *(int4*)(sK + (32 + skey) * LDK + skc) = kr1;
    {
      const u16* pv0 = (const u16*)&vr0;
      const u16* pv1 = (const u16*)&vr1;
#pragma unroll
      for (int j = 0; j < 8; ++j) {
        sVt[(w * 8 + j) * LDK + l] = pv0[j];
        sVt[((4 + w) * 8 + j) * LDK + l] = pv1[j];
      }
    }
    if (kt + 1 < nkt) {
      const u16* pk = KgB + (size_t)((kt + 1) * 64) * Dn;
      const u16* pv = VgB + (size_t)((kt + 1) * 64) * Dn;
      kr0 = *(const int4*)(pk + (size_t)skey * Dn + skc);
      kr1 = *(const int4*)(pk + (size_t)(32 + skey) * Dn + skc);
      vr0 = *(const int4*)(pv + (size_t)l * Dn + w * 8);
      vr1 = *(const int4*)(pv + (size_t)l * Dn + (4 + w) * 8);
    }
    asm volatile("s_waitcnt lgkmcnt(0)" ::: "memory");
    __builtin_amdgcn_s_barrier();        // B: sK/sVt visible to all waves
    __builtin_amdgcn_sched_barrier(0);
    const int kb = kt * 64;
    f32x4 s[4] = {};
#pragma unroll
    for (int nf = 0; nf < 4; ++nf)
#pragma unroll
      for (int ks = 0; ks < 2; ++ks) {
        bf16x8 kf = *(const bf16x8*)(sK + (nf * 16 + lr) * LDK + ks * 32 + lk);
        s[nf] = MFMA16(qf[ks], kf, s[nf]);
      }
    const int prow = w * 16 + lg;
    if (kt < qt) {
#pragma unroll
      for (int r = 0; r < 4; ++r)
#pragma unroll
        for (int nf = 0; nf < 4; ++nf)
          sP[(prow + r) * LDK + nf * 16 + lr] = f2bf_t(EXP2(s[nf][r]) * inv[r]);
    } else {
#pragma unroll
      for (int r = 0; r < 4; ++r)
#pragma unroll
        for (int nf = 0; nf < 4; ++nf) {
          float p = (kb + nf * 16 + lr <= qg + r) ? EXP2(s[nf][r]) * inv[r] : 0.f;
          sP[(prow + r) * LDK + nf * 16 + lr] = f2bf_t(p);
        }
    }
    // no barrier: sP rows are per-wave; intra-wave lgkmcnt ordering suffices
#pragma unroll
    for (int ks = 0; ks < 2; ++ks) {
      bf16x8 ap, bv[4];
      ap = *(const bf16x8*)(sP + (w * 16 + lr) * LDK + ks * 32 + lk);
#pragma unroll
      for (int nf = 0; nf < 4; ++nf)
        bv[nf] = *(const bf16x8*)(sVt + (nf * 16 + lr) * LDK + ks * 32 + lk);
#pragma unroll
      for (int nf = 0; nf < 4; ++nf)
        accO[nf] = MFMA16(ap, bv[nf], accO[nf]);
    }
    // per-wave coalesced non-temporal f32 attn stores of this wave's 16 rows
#pragma unroll
    for (int i = 0; i < 4; ++i) {
      int fidx = i * 64 + l;
      int row = w * 16 + (fidx >> 4), c4 = fidx & 15;
      uint2 pk = *(const uint2*)(sP + row * LDK + c4 * 4);
      f32x4 o;
      o[0] = bf2f(pk.x & 0xffffu);
      o[1] = bf2f(pk.x >> 16);
      o[2] = bf2f(pk.y & 0xffffu);
      o[3] = bf2f(pk.y >> 16);
      __builtin_nontemporal_store(o, (f32x4*)(attnBH + (size_t)(qt * 64 + row) * Tn + kb + c4 * 4));
    }
  }

  // zero-fill columns beyond causal extent of this q-tile (non-temporal)
  {
    const int zstart = nkt * 64;
    if (zstart < Tn) {
      f32x4 z4 = {0.f, 0.f, 0.f, 0.f};
      for (int rr = 0; rr < 64; ++rr) {
        float* rp = attnBH + (size_t)(qt * 64 + rr) * Tn;
        for (int cc = zstart + 4 * t; cc < Tn; cc += 1024)
          __builtin_nontemporal_store(z4, (f32x4*)(rp + cc));
      }
    }
  }

  // O (bf16) into [B*T][D] at this head's column block
  {
    int row = b * Tn + qt * 64 + w * 16 + lg;
#pragma unroll
    for (int nf = 0; nf < 4; ++nf) {
      int col = h * 64 + nf * 16 + lr;
#pragma unroll
      for (int r = 0; r < 4; ++r)
        Ob[(size_t)(row + r) * Dn + col] = f2bf(accO[nf][r]);
    }
  }
}

extern "C" void kernel_launch(void* const* d_in, const int* in_sizes, int n_in,
                              void* d_out, int out_size, void* d_ws, size_t ws_size,
                              hipStream_t stream) {
  const float* xq  = (const float*)d_in[0];
  const float* xkv = (const float*)d_in[1];
  // d_in[2] = mask (causal, implicit)
  const float* Wq = (const float*)d_in[3];
  const float* bq = (const float*)d_in[4];
  const float* Wk = (const float*)d_in[5];
  const float* bk = (const float*)d_in[6];
  const float* Wv = (const float*)d_in[7];
  const float* bv = (const float*)d_in[8];
  const float* Wo = (const float*)d_in[9];
  const float* bo = (const float*)d_in[10];

  float* out  = (float*)d_out;                  // [4096][1024]
  float* attn = out + (size_t)4096 * 1024;      // [2][16][2048][2048]

  u16* XQ  = (u16*)d_ws;
  u16* XKV = XQ  + (size_t)4096 * 1024;
  u16* WQb = XKV + (size_t)4096 * 1024;
  u16* WKb = WQb + (size_t)1024 * 1024;
  u16* WVb = WKb + (size_t)1024 * 1024;
  u16* WOb = WVb + (size_t)1024 * 1024;
  u16* Qb  = WOb + (size_t)1024 * 1024;
  u16* Kb  = Qb  + (size_t)4096 * 1024;
  u16* Vb  = Kb  + (size_t)4096 * 1024;
  u16* Ob  = Vb  + (size_t)4096 * 1024;

  cvt_x2<<<dim3(4096, 2), 256, 0, stream>>>(xq, xkv, XQ, XKV);
  cvt_w4<<<dim3(1024, 4), 256, 0, stream>>>(Wq, Wk, Wv, Wo, WQb, WKb, WVb, WOb);

  gemm_qkv<<<dim3(8, 32, 3), 256, 0, stream>>>(XQ, XKV, WQb, WKb, WVb,
                                               bq, bk, bv, Qb, Kb, Vb);

  attn_fused<<<dim3(32, 16, 2), 256, 0, stream>>>(Qb, Kb, Vb, attn, Ob);

  gemm_o<<<dim3(8, 64), 256, 0, stream>>>(Ob, WOb, bo, out);
}